// Round 1
// baseline (27.595 us; speedup 1.0000x reference)
//
#include <hip/hip_runtime.h>
#include <math.h>

#define Bn 4
#define Pn 24
#define Gn 24
#define Hd 512
#define Wd 512
#define NOBJ (Bn * Pn)
#define SPLIT 16
#define IOU_THRESH 0.5f
#define LOG_CLAMP -100.0f

// ws layout:
//   params: int32 [NOBJ][6]  (keep, gidx, y1, x1, y2, x2)   at offset 0
//   acc:    float [NOBJ][4]  (bce_sum, inter, sum_p, sum_t) at offset 4096
#define ACC_OFF 4096

__global__ void match_kernel(const float* __restrict__ pred_boxes,
                             const float* __restrict__ gt_boxes,
                             const int* __restrict__ pred_valid,
                             const int* __restrict__ gt_valid,
                             int* __restrict__ params,
                             float* __restrict__ acc) {
    int i = threadIdx.x;
    // zero the accumulators (ws is poisoned with 0xAA by the harness)
    for (int k = i; k < NOBJ * 4; k += blockDim.x) acc[k] = 0.0f;
    if (i >= NOBJ) return;
    int b = i / Pn;
    const float* pb = pred_boxes + (size_t)i * 4;
    float a0 = pb[0], a1 = pb[1], a2 = pb[2], a3 = pb[3];
    float area_a = (a2 - a0) * (a3 - a1);
    float best = -1.0f;
    int bestg = 0;
    for (int g = 0; g < Gn; ++g) {
        const float* gb = gt_boxes + ((size_t)b * Gn + g) * 4;
        float b0 = gb[0], b1 = gb[1], b2 = gb[2], b3 = gb[3];
        float area_b = (b2 - b0) * (b3 - b1);
        float ih = fmaxf(fminf(a2, b2) - fmaxf(a0, b0), 0.0f);
        float iw = fmaxf(fminf(a3, b3) - fmaxf(a1, b1), 0.0f);
        float inter = ih * iw;
        float uni = area_a + area_b - inter;
        float iou = (uni == 0.0f) ? 0.0f : inter / uni;
        if (gt_valid[b * Gn + g] == 0) iou = -1.0f;
        if (iou > best) { best = iou; bestg = g; }  // first-max == jnp.argmax
    }
    int keep = (best >= IOU_THRESH) && (pred_valid[i] != 0);
    // jnp.round is round-half-to-even -> rintf (default FE_TONEAREST)
    int y1 = max(0, (int)rintf(a0 * (float)Hd));
    int x1 = max(0, (int)rintf(a1 * (float)Wd));
    int y2 = min((int)rintf(a2 * (float)Hd), Hd - 1);
    int x2 = min((int)rintf(a3 * (float)Wd), Wd - 1);
    int* q = params + i * 6;
    q[0] = keep; q[1] = bestg; q[2] = y1; q[3] = x1; q[4] = y2; q[5] = x2;
}

__global__ void region_kernel(const float* __restrict__ pred_masks,
                              const float* __restrict__ gt_masks,
                              const int* __restrict__ params,
                              float* __restrict__ acc) {
    int obj = blockIdx.x;          // b*Pn + p
    int part = blockIdx.y;         // 0..SPLIT-1
    const int* q = params + obj * 6;
    if (q[0] == 0) return;         // not kept: contributes nothing to total
    int gidx = q[1], y1 = q[2], x1 = q[3], y2 = q[4], x2 = q[5];
    if (y2 < y1 || x2 < x1) return;  // empty region: sums stay 0
    int Hr = y2 - y1 + 1, Wr = x2 - x1 + 1;
    int N = Hr * Wr;
    int b = obj / Pn;
    const float* pm = pred_masks + (size_t)obj * Hd * Wd;
    const float* gm = gt_masks + ((size_t)b * Gn + gidx) * Hd * Wd;

    float bce = 0.0f, inter = 0.0f, sp = 0.0f, st = 0.0f;
    int stride = (int)gridDim.y * (int)blockDim.x;
    for (int idx = part * (int)blockDim.x + (int)threadIdx.x; idx < N; idx += stride) {
        int r = y1 + idx / Wr;
        int c = x1 + idx % Wr;
        float pv = pm[r * Wd + c];
        float tv = gm[r * Wd + c];
        float lp = fmaxf(logf(pv), LOG_CLAMP);
        float l1 = fmaxf(log1pf(-pv), LOG_CLAMP);
        bce += -(tv * lp + (1.0f - tv) * l1);
        inter += pv * tv;
        sp += pv;
        st += tv;
    }

    // block reduce: 4 waves of 64, then LDS
    float v0 = bce, v1 = inter, v2 = sp, v3 = st;
    for (int o = 32; o > 0; o >>= 1) {
        v0 += __shfl_down(v0, o, 64);
        v1 += __shfl_down(v1, o, 64);
        v2 += __shfl_down(v2, o, 64);
        v3 += __shfl_down(v3, o, 64);
    }
    __shared__ float red[4][4];  // [wave][quantity]
    int lane = threadIdx.x & 63, w = threadIdx.x >> 6;
    if (lane == 0) { red[w][0] = v0; red[w][1] = v1; red[w][2] = v2; red[w][3] = v3; }
    __syncthreads();
    if (threadIdx.x < 4) {
        float s = red[0][threadIdx.x] + red[1][threadIdx.x] + red[2][threadIdx.x] + red[3][threadIdx.x];
        atomicAdd(&acc[obj * 4 + (int)threadIdx.x], s);
    }
}

__global__ void finalize_kernel(const int* __restrict__ params,
                                const float* __restrict__ acc,
                                float* __restrict__ out) {
    int i = threadIdx.x;  // 128 threads, 2 waves
    float loss = 0.0f, nk = 0.0f;
    if (i < NOBJ) {
        const int* q = params + i * 6;
        if (q[0]) {
            nk = 1.0f;
            int y1 = q[2], x1 = q[3], y2 = q[4], x2 = q[5];
            float cnt = (y2 >= y1 && x2 >= x1) ? (float)((y2 - y1 + 1) * (x2 - x1 + 1)) : 0.0f;
            float bce = acc[i * 4 + 0] / fmaxf(cnt, 1.0f);
            float inter = acc[i * 4 + 1], sp = acc[i * 4 + 2], st = acc[i * 4 + 3];
            float dice = 1.0f - (2.0f * inter + 1.0f) / (sp + st + 1.0f);
            loss = bce + dice;
        }
    }
    float v0 = loss, v1 = nk;
    for (int o = 32; o > 0; o >>= 1) {
        v0 += __shfl_down(v0, o, 64);
        v1 += __shfl_down(v1, o, 64);
    }
    __shared__ float red[2][2];
    if ((threadIdx.x & 63) == 0) { red[threadIdx.x >> 6][0] = v0; red[threadIdx.x >> 6][1] = v1; }
    __syncthreads();
    if (threadIdx.x == 0) {
        float total = red[0][0] + red[1][0];
        float nobj = red[0][1] + red[1][1];
        out[0] = total / fmaxf(nobj, 1.0f);
    }
}

extern "C" void kernel_launch(void* const* d_in, const int* in_sizes, int n_in,
                              void* d_out, int out_size, void* d_ws, size_t ws_size,
                              hipStream_t stream) {
    const float* pred_masks = (const float*)d_in[0];
    const float* pred_boxes = (const float*)d_in[1];
    const float* gt_boxes   = (const float*)d_in[2];
    const float* gt_masks   = (const float*)d_in[3];
    const int*   pred_valid = (const int*)d_in[4];
    const int*   gt_valid   = (const int*)d_in[5];
    float* out = (float*)d_out;

    int*   params = (int*)d_ws;
    float* acc    = (float*)((char*)d_ws + ACC_OFF);

    match_kernel<<<1, 128, 0, stream>>>(pred_boxes, gt_boxes, pred_valid, gt_valid, params, acc);
    region_kernel<<<dim3(NOBJ, SPLIT), 256, 0, stream>>>(pred_masks, gt_masks, params, acc);
    finalize_kernel<<<1, 128, 0, stream>>>(params, acc, out);
}

// Round 2
// 24.897 us; speedup vs baseline: 1.1084x; 1.1084x over previous
//
#include <hip/hip_runtime.h>
#include <math.h>

#define Bn 4
#define Pn 24
#define Gn 24
#define Hd 512
#define Wd 512
#define NOBJ (Bn * Pn)
#define SPLIT 16
#define IOU_THRESH 0.5f
#define LOG_CLAMP -100.0f

// ws layout: acc float[NOBJ][SPLIT][4]  (bce_sum, inter, sum_p, sum_t)
// Every block writes its slot unconditionally -> no zero-init, no atomics.

__device__ __forceinline__ void match_obj(const float* __restrict__ pred_boxes,
                                          const float* __restrict__ gt_boxes,
                                          const int* __restrict__ pred_valid,
                                          const int* __restrict__ gt_valid,
                                          int obj, int& keep, int& gidx,
                                          int& y1, int& x1, int& y2, int& x2) {
    int b = obj / Pn;
    const float* pb = pred_boxes + (size_t)obj * 4;
    float a0 = pb[0], a1 = pb[1], a2 = pb[2], a3 = pb[3];
    float area_a = (a2 - a0) * (a3 - a1);
    float best = -1.0f;
    gidx = 0;
    for (int g = 0; g < Gn; ++g) {
        const float* gb = gt_boxes + ((size_t)b * Gn + g) * 4;
        float b0 = gb[0], b1 = gb[1], b2 = gb[2], b3 = gb[3];
        float area_b = (b2 - b0) * (b3 - b1);
        float ih = fmaxf(fminf(a2, b2) - fmaxf(a0, b0), 0.0f);
        float iw = fmaxf(fminf(a3, b3) - fmaxf(a1, b1), 0.0f);
        float inter = ih * iw;
        float uni = area_a + area_b - inter;
        float iou = (uni == 0.0f) ? 0.0f : inter / uni;
        if (gt_valid[b * Gn + g] == 0) iou = -1.0f;
        if (iou > best) { best = iou; gidx = g; }  // first-max == jnp.argmax
    }
    keep = (best >= IOU_THRESH) && (pred_valid[obj] != 0);
    // jnp.round is round-half-to-even -> rintf (default FE_TONEAREST)
    y1 = max(0, (int)rintf(a0 * (float)Hd));
    x1 = max(0, (int)rintf(a1 * (float)Wd));
    y2 = min((int)rintf(a2 * (float)Hd), Hd - 1);
    x2 = min((int)rintf(a3 * (float)Wd), Wd - 1);
}

__global__ void region_kernel(const float* __restrict__ pred_masks,
                              const float* __restrict__ gt_masks,
                              const float* __restrict__ pred_boxes,
                              const float* __restrict__ gt_boxes,
                              const int* __restrict__ pred_valid,
                              const int* __restrict__ gt_valid,
                              float* __restrict__ acc) {
    int obj = blockIdx.x;   // b*Pn + p
    int part = blockIdx.y;  // 0..SPLIT-1

    int keep, gidx, y1, x1, y2, x2;
    match_obj(pred_boxes, gt_boxes, pred_valid, gt_valid, obj, keep, gidx, y1, x1, y2, x2);

    float v0 = 0.0f, v1 = 0.0f, v2 = 0.0f, v3 = 0.0f;
    if (keep) {
        int Hr = y2 - y1 + 1, Wr = x2 - x1 + 1;
        if (Hr > 0 && Wr > 0) {
            int N = Hr * Wr;
            const float* pm = pred_masks + (size_t)obj * Hd * Wd;
            const float* gm = gt_masks + ((size_t)(obj / Pn) * Gn + gidx) * Hd * Wd;
            const int stride = SPLIT * 256;
            for (int idx = part * 256 + (int)threadIdx.x; idx < N; idx += stride) {
                int r = y1 + idx / Wr;
                int c = x1 + idx % Wr;
                float pv = pm[r * Wd + c];
                float tv = gm[r * Wd + c];
                // t is exactly 0/1: select the needed log argument.
                // 1-p is exact for p>=0.5 (Sterbenz), <=1ulp otherwise.
                float xarg = (tv > 0.5f) ? pv : (1.0f - pv);
                v0 -= fmaxf(logf(xarg), LOG_CLAMP);
                v1 = fmaf(pv, tv, v1);
                v2 += pv;
                v3 += tv;
            }
        }
    }

    // block reduce 256 -> 4 sums
    for (int o = 32; o > 0; o >>= 1) {
        v0 += __shfl_down(v0, o, 64);
        v1 += __shfl_down(v1, o, 64);
        v2 += __shfl_down(v2, o, 64);
        v3 += __shfl_down(v3, o, 64);
    }
    __shared__ float red[4][4];
    int lane = threadIdx.x & 63, w = threadIdx.x >> 6;
    if (lane == 0) { red[w][0] = v0; red[w][1] = v1; red[w][2] = v2; red[w][3] = v3; }
    __syncthreads();
    if (threadIdx.x < 4) {
        float s = red[0][threadIdx.x] + red[1][threadIdx.x] +
                  red[2][threadIdx.x] + red[3][threadIdx.x];
        acc[((size_t)obj * SPLIT + part) * 4 + threadIdx.x] = s;  // unconditional slot write
    }
}

__global__ void finalize_kernel(const float* __restrict__ acc,
                                const float* __restrict__ pred_boxes,
                                const float* __restrict__ gt_boxes,
                                const int* __restrict__ pred_valid,
                                const int* __restrict__ gt_valid,
                                float* __restrict__ out) {
    int i = threadIdx.x;  // 128 threads, 2 waves
    float loss = 0.0f, nk = 0.0f;
    if (i < NOBJ) {
        int keep, gidx, y1, x1, y2, x2;
        match_obj(pred_boxes, gt_boxes, pred_valid, gt_valid, i, keep, gidx, y1, x1, y2, x2);
        if (keep) {
            nk = 1.0f;
            float s0 = 0.0f, s1 = 0.0f, s2 = 0.0f, s3 = 0.0f;
            const float* a = acc + (size_t)i * SPLIT * 4;
            for (int p = 0; p < SPLIT; ++p) {
                s0 += a[p * 4 + 0];
                s1 += a[p * 4 + 1];
                s2 += a[p * 4 + 2];
                s3 += a[p * 4 + 3];
            }
            float cnt = (y2 >= y1 && x2 >= x1) ? (float)((y2 - y1 + 1) * (x2 - x1 + 1)) : 0.0f;
            float bce = s0 / fmaxf(cnt, 1.0f);
            float dice = 1.0f - (2.0f * s1 + 1.0f) / (s2 + s3 + 1.0f);
            loss = bce + dice;
        }
    }
    float v0 = loss, v1 = nk;
    for (int o = 32; o > 0; o >>= 1) {
        v0 += __shfl_down(v0, o, 64);
        v1 += __shfl_down(v1, o, 64);
    }
    __shared__ float red[2][2];
    if ((threadIdx.x & 63) == 0) { red[threadIdx.x >> 6][0] = v0; red[threadIdx.x >> 6][1] = v1; }
    __syncthreads();
    if (threadIdx.x == 0) {
        float total = red[0][0] + red[1][0];
        float nobj = red[0][1] + red[1][1];
        out[0] = total / fmaxf(nobj, 1.0f);
    }
}

extern "C" void kernel_launch(void* const* d_in, const int* in_sizes, int n_in,
                              void* d_out, int out_size, void* d_ws, size_t ws_size,
                              hipStream_t stream) {
    const float* pred_masks = (const float*)d_in[0];
    const float* pred_boxes = (const float*)d_in[1];
    const float* gt_boxes   = (const float*)d_in[2];
    const float* gt_masks   = (const float*)d_in[3];
    const int*   pred_valid = (const int*)d_in[4];
    const int*   gt_valid   = (const int*)d_in[5];
    float* out = (float*)d_out;
    float* acc = (float*)d_ws;  // [NOBJ][SPLIT][4]

    region_kernel<<<dim3(NOBJ, SPLIT), 256, 0, stream>>>(
        pred_masks, gt_masks, pred_boxes, gt_boxes, pred_valid, gt_valid, acc);
    finalize_kernel<<<1, 128, 0, stream>>>(
        acc, pred_boxes, gt_boxes, pred_valid, gt_valid, out);
}